// Round 6
// baseline (142.011 us; speedup 1.0000x reference)
//
#include <hip/hip_runtime.h>
#include <stdint.h>

typedef short bf16x8 __attribute__((ext_vector_type(8)));
typedef unsigned short u16x8 __attribute__((ext_vector_type(8)));
typedef float f32x4 __attribute__((ext_vector_type(4)));
typedef float f32x8 __attribute__((ext_vector_type(8)));

constexpr int BT_TOT = 768;   // B*T
constexpr int M_N    = 512;   // nodes (contraction length for stage 1)
constexpr int DD     = 64;    // Din = Dout
constexpr int WROW   = 72;    // W' row stride in route_mm (144B, bank step 4)

__device__ __forceinline__ unsigned short f2bf(float f) {
  unsigned u = __builtin_bit_cast(unsigned, f);
  u += 0x7fffu + ((u >> 16) & 1u);          // RNE
  return (unsigned short)(u >> 16);
}
__device__ __forceinline__ unsigned pk2(float a, float b) {
  return (unsigned)f2bf(a) | ((unsigned)f2bf(b) << 16);
}

// ---------------- prep: adj f32 -> bf16 (once) ----------------
__global__ __launch_bounds__(256)
void prep_adj(const float* __restrict__ adjg, unsigned short* __restrict__ wsadj) {
  int i = (blockIdx.x * 256 + threadIdx.x) * 8;
  f32x8 a = *(const f32x8*)(adjg + i);
  u16x8 r;
  #pragma unroll
  for (int j = 0; j < 8; ++j) r[j] = f2bf(a[j]);
  *(u16x8*)(wsadj + i) = r;
}

// ---------------- Kernel A ----------------
// H[bt][m][d] = sum_n adj[m][n] * x[bt][n][d]  (bf16), one WG per bt.
// v6: coalesced x loads (1KB/wave contiguous) + in-register 4x4 lane transpose
// (shfl_xor butterfly) + T14 issue-early/write-late so load latency hides
// under the MFMA phase. xT layout and MFMA read pattern identical to v5
// (numerically verified): elem(d,n) at byte d*256 + ((n>>3)^(d&7))*16 + (n&7)*2.
template<bool WS>
__global__ __launch_bounds__(512, 4)
void gconv_h(const float* __restrict__ xg,             // [768][512][64] f32
             const float* __restrict__ adjf,           // [512][512] f32 (fallback)
             const unsigned short* __restrict__ adjb,  // [512][512] bf16 (ws path)
             char* __restrict__ hout)
{
  __shared__ unsigned short xTc[2][64 * 128];   // 2 x 16 KB -> 2 WG/CU

  const int bt   = blockIdx.x;
  const int tid  = threadIdx.x;
  const int lane = tid & 63;
  const int wv   = tid >> 6;        // wave 0..7: owns m in [wv*64, wv*64+64)
  const int l15  = lane & 15;
  const int gg   = lane >> 4;       // k-group 0..3
  const int r4   = lane >> 4;       // transpose-group row (n-offset 0..3)
  const int c4   = lane & 15;       // d-quad 0..15
  const int nrow = tid >> 4;        // staging row 0..31 (per sweep)

  const float* xb = xg + (size_t)bt * (M_N * DD);

  f32x4 xv[4];
  // ---- staging: coalesced load of 4 sweeps (32 n each) for chunk c ----
  auto load_chunk = [&](int c) {
    #pragma unroll
    for (int s = 0; s < 4; ++s)
      xv[s] = *(const f32x4*)(xb + (size_t)(c*128 + s*32 + nrow) * DD + c4*4);
  };
  // ---- pack f32->bf16, 4x4 lane transpose, single b64 write per sweep ----
  auto pack_chunk = [&](int c) {
    unsigned short* xt = &xTc[c & 1][0];
    const int d = c4*4 + r4;                  // this lane's final d
    #pragma unroll
    for (int s = 0; s < 4; ++s) {
      unsigned u0 = pk2(xv[s].x, xv[s].y);    // {M[r][0], M[r][1]}
      unsigned u1 = pk2(xv[s].z, xv[s].w);    // {M[r][2], M[r][3]}
      unsigned t0 = __shfl_xor(u0, 32);       // partner r^2
      unsigned t1 = __shfl_xor(u1, 32);
      unsigned v0 = (r4 & 2) ? t1 : u0;       // = M[r&1][cb]
      unsigned v1 = (r4 & 2) ? u1 : t0;       // = M[2+(r&1)][cb]
      unsigned s0 = __shfl_xor(v0, 16);       // partner r^1
      unsigned s1 = __shfl_xor(v1, 16);
      unsigned F0 = (r4 & 1) ? ((s0 >> 16) | (v0 & 0xFFFF0000u))
                             : ((v0 & 0xFFFFu) | (s0 << 16));   // {x[n0][d],x[n1][d]}
      unsigned F1 = (r4 & 1) ? ((s1 >> 16) | (v1 & 0xFFFF0000u))
                             : ((v1 & 0xFFFFu) | (s1 << 16));   // {x[n2][d],x[n3][d]}
      const int n4 = s*8 + wv;                // n-quad index within chunk
      uint2 o; o.x = F0; o.y = F1;
      *(uint2*)((char*)xt + d*256 + (((n4 >> 1) ^ (d & 7)) * 16) + (n4 & 1)*8) = o;
    }
  };

  load_chunk(0);
  pack_chunk(0);
  __syncthreads();

  f32x4 acc[4][4];
  #pragma unroll
  for (int mt = 0; mt < 4; ++mt)
    #pragma unroll
    for (int dt = 0; dt < 4; ++dt) acc[mt][dt] = f32x4{0.f,0.f,0.f,0.f};

  #pragma unroll
  for (int c = 0; c < 4; ++c) {
    unsigned short* xt = &xTc[c & 1][0];
    if (c < 3) load_chunk(c + 1);   // issue early: in flight across the MFMA phase

    #pragma unroll
    for (int kl = 0; kl < 4; ++kl) {
      const int kg = c*4 + kl;                 // global k-slice (32 n each)
      bf16x8 afr[4];
      #pragma unroll
      for (int mt = 0; mt < 4; ++mt) {
        const int m = wv*64 + mt*16 + l15;
        if (WS) {
          afr[mt] = __builtin_bit_cast(bf16x8,
              *(const u16x8*)(adjb + (size_t)m*M_N + kg*32 + gg*8));
        } else {
          f32x8 a = *(const f32x8*)(adjf + (size_t)m*M_N + kg*32 + gg*8);
          u16x8 r;
          #pragma unroll
          for (int j = 0; j < 8; ++j) r[j] = f2bf(a[j]);
          afr[mt] = __builtin_bit_cast(bf16x8, r);
        }
      }
      #pragma unroll
      for (int dt = 0; dt < 4; ++dt) {
        const int d = dt*16 + l15;
        bf16x8 bfx = __builtin_bit_cast(bf16x8,
            *(const u16x8*)(xt + d*128 + (((kl*4 + gg) ^ (l15 & 7)))*8));
        #pragma unroll
        for (int mt = 0; mt < 4; ++mt)
          acc[mt][dt] = __builtin_amdgcn_mfma_f32_16x16x32_bf16(afr[mt], bfx,
                                                                acc[mt][dt], 0,0,0);
      }
    }

    if (c < 3) pack_chunk(c + 1);   // write late: vmcnt-wait lands here, not at barrier
    __syncthreads();
  }

  // epilogue: H store (bf16, low half of each d_out row) — verified
  #pragma unroll
  for (int mt = 0; mt < 4; ++mt)
    #pragma unroll
    for (int dt = 0; dt < 4; ++dt)
      #pragma unroll
      for (int r = 0; r < 4; ++r) {
        int m = wv*64 + mt*16 + gg*4 + r;      // C row = (lane>>4)*4 + reg
        int d = dt*16 + l15;
        *(unsigned short*)(hout + ((size_t)bt*M_N + m)*256 + 2*d)
            = f2bf(acc[mt][dt][r]);
      }
}

// ---------------- Kernel B (unchanged, verified) ----------------
__global__ __launch_bounds__(256, 4)
void route_mm(const char* __restrict__ hin,
              const float* __restrict__ wgt,
              const float* __restrict__ bias,
              float* __restrict__ outg)
{
  __shared__ unsigned short wb[128 * WROW];

  const int m0    = blockIdx.x * 2;
  const int btblk = blockIdx.y * 64;
  const int tid   = threadIdx.x;
  const int lane  = tid & 63;
  const int wv    = tid >> 6;
  const int l15   = lane & 15;
  const int gg    = lane >> 4;
  const int dp    = tid & 31;
  const int lo    = tid >> 5;

  { const float* q = wgt + ((size_t)m0*64 + dp*2)*64 + lo*8;
    f32x8 w0 = *(const f32x8*)q;          f32x8 w1 = *(const f32x8*)(q+64);
    f32x8 w2 = *(const f32x8*)(q+4096);   f32x8 w3 = *(const f32x8*)(q+4160);
    #pragma unroll
    for (int e = 0; e < 8; ++e) {
      int lrow = lo*8 + e;
      unsigned v0 = pk2(w0[e], w1[e]);
      unsigned v1 = pk2(w2[e], w3[e]);
      *(unsigned*)(wb + lrow*WROW + dp*2)        = v0;
      *(unsigned*)(wb + (64 + lrow)*WROW + dp*2) = v1;
    }
  }
  __syncthreads();

  const int btw0 = btblk + wv*16;

  #pragma unroll
  for (int mm = 0; mm < 2; ++mm) {
    const int m = m0 + mm;
    bf16x8 afr[2];
    #pragma unroll
    for (int ks = 0; ks < 2; ++ks) {
      const char* hp = hin + ((size_t)(btw0 + l15)*M_N + m)*256 + ks*64 + gg*16;
      afr[ks] = __builtin_bit_cast(bf16x8, *(const u16x8*)hp);
    }
    f32x4 acc[4];
    #pragma unroll
    for (int lt = 0; lt < 4; ++lt) acc[lt] = f32x4{0.f,0.f,0.f,0.f};
    #pragma unroll
    for (int lt = 0; lt < 4; ++lt)
      #pragma unroll
      for (int ks = 0; ks < 2; ++ks) {
        bf16x8 bfr = __builtin_bit_cast(bf16x8,
            *(const u16x8*)(wb + (mm*64 + lt*16 + l15)*WROW + ks*32 + gg*8));
        acc[lt] = __builtin_amdgcn_mfma_f32_16x16x32_bf16(afr[ks], bfr, acc[lt], 0,0,0);
      }
    #pragma unroll
    for (int lt = 0; lt < 4; ++lt) {
      float bv = bias[m*64 + lt*16 + l15];
      #pragma unroll
      for (int r = 0; r < 4; ++r) {
        size_t row = (size_t)(btw0 + gg*4 + r)*M_N + m;
        outg[row*64 + lt*16 + l15] = acc[lt][r] + bv;
      }
    }
  }
}

extern "C" void kernel_launch(void* const* d_in, const int* in_sizes, int n_in,
                              void* d_out, int out_size, void* d_ws, size_t ws_size,
                              hipStream_t stream) {
  const float* xg   = (const float*)d_in[0];
  const float* adjg = (const float*)d_in[1];
  const float* wgt  = (const float*)d_in[2];
  const float* bg   = (const float*)d_in[3];

  const size_t adj_bf_bytes = (size_t)M_N * M_N * 2;   // 512 KB
  if (ws_size >= adj_bf_bytes) {
    unsigned short* wsadj = (unsigned short*)d_ws;
    prep_adj<<<dim3(M_N * M_N / (256 * 8)), dim3(256), 0, stream>>>(adjg, wsadj);
    gconv_h<true><<<dim3(BT_TOT), dim3(512), 0, stream>>>(
        xg, adjg, wsadj, (char*)d_out);
  } else {
    gconv_h<false><<<dim3(BT_TOT), dim3(512), 0, stream>>>(
        xg, adjg, nullptr, (char*)d_out);
  }
  route_mm<<<dim3(M_N/2, BT_TOT/64), dim3(256), 0, stream>>>(
      (const char*)d_out, wgt, bg, (float*)d_out);
}

// Round 7
// 99.452 us; speedup vs baseline: 1.4279x; 1.4279x over previous
//
#include <hip/hip_runtime.h>
#include <stdint.h>

typedef short bf16x8 __attribute__((ext_vector_type(8)));
typedef unsigned short u16x8 __attribute__((ext_vector_type(8)));
typedef float f32x4 __attribute__((ext_vector_type(4)));
typedef float f32x8 __attribute__((ext_vector_type(8)));

constexpr int BT_TOT = 768;   // B*T
constexpr int M_N    = 512;   // nodes (contraction length for stage 1)
constexpr int DD     = 64;    // Din = Dout
constexpr int WROW   = 72;    // W' row stride in route_mm (144B, bank step 4)

__device__ __forceinline__ unsigned short f2bf(float f) {
  unsigned u = __builtin_bit_cast(unsigned, f);
  u += 0x7fffu + ((u >> 16) & 1u);          // RNE
  return (unsigned short)(u >> 16);
}
__device__ __forceinline__ unsigned pk2(float a, float b) {
  return (unsigned)f2bf(a) | ((unsigned)f2bf(b) << 16);
}

// ---------------- prep: adj f32 -> bf16 (once) ----------------
__global__ __launch_bounds__(256)
void prep_adj(const float* __restrict__ adjg, unsigned short* __restrict__ wsadj) {
  int i = (blockIdx.x * 256 + threadIdx.x) * 8;
  f32x8 a = *(const f32x8*)(adjg + i);
  u16x8 r;
  #pragma unroll
  for (int j = 0; j < 8; ++j) r[j] = f2bf(a[j]);
  *(u16x8*)(wsadj + i) = r;
}

// ---------------- Kernel A v7 ----------------
// H[bt][m][d] = sum_n adj[m][n]*x[bt][n][d] (bf16 into low 128B of d_out rows).
// WG = 2 bt x 128 m. adj chunk STAGED IN LDS (amortized over 2 bt, swizzled via
// inverse-swizzled source); x chunk butterfly-transposed (verified v6 path).
// Grid swizzle: the 4 m-blocks of one bt-pair are consecutive slots on ONE XCD
// -> x slice read once from L3 then L2-hits; adj L2-resident per XCD.
template<bool WS>
__global__ __launch_bounds__(512, 2)
void gconv_h(const float* __restrict__ xg,             // [768][512][64] f32
             const float* __restrict__ adjf,           // [512][512] f32 (fallback)
             const unsigned short* __restrict__ adjb,  // [512][512] bf16 (ws path)
             char* __restrict__ hout)
{
  __shared__ char lds[2][32768];   // per buf: [0,16K) adj[128m][64n], [16K,32K) xT[2bt][64d][64n]

  const int wid  = blockIdx.x;         // 0..1535
  const int xcd  = wid & 7;
  const int slot = wid >> 3;           // 0..191 (slot order within an XCD)
  const int mb   = slot & 3;           // m-block 0..3 (consecutive slots share btg)
  const int btg  = xcd + 8 * (slot >> 2);   // 0..383
  const int bt0  = btg * 2;

  const int tid  = threadIdx.x;
  const int lane = tid & 63;
  const int wv   = tid >> 6;           // 0..7
  const int l15  = lane & 15;
  const int gg   = lane >> 4;          // k-group 0..3 (also butterfly row r4)
  const int c4   = lane & 15;          // d-quad for staging
  const int wb   = wv & 1;             // bt within pair
  const int wm   = wv >> 1;            // m-quarter (32 m) / n-phase for staging

  // adj staging indices: linear LDS addr L = i*8192 + tid*16 holds row m_loc = i*64+(tid>>3),
  // oct (tid&7); inverse-swizzle the SOURCE oct so the swizzled READ is bank-spread.
  const int mlo  = tid >> 3;                       // i=0 row; i=1 adds 64 (same &7)
  const int oct  = (tid & 7) ^ (mlo & 7);

  f32x4 xv[4];
  u16x8 ab[2];
  f32x8 af_[2];

  auto load_adj = [&](int c) {
    const size_t e0 = (size_t)(mb*128 + mlo     ) * M_N + c*64 + oct*8;
    const size_t e1 = (size_t)(mb*128 + mlo + 64) * M_N + c*64 + oct*8;
    if (WS) { ab[0] = *(const u16x8*)(adjb + e0); ab[1] = *(const u16x8*)(adjb + e1); }
    else    { af_[0] = *(const f32x8*)(adjf + e0); af_[1] = *(const f32x8*)(adjf + e1); }
  };
  auto load_x = [&](int c) {
    #pragma unroll
    for (int s = 0; s < 4; ++s) {   // wave-uniform n-quad n4 = s*4+wm; lanes: 4 n x 64 d = 1KB contig
      const int n4 = s*4 + wm;
      xv[s] = *(const f32x4*)(xg + ((size_t)(bt0 + wb) * M_N + c*64 + n4*4 + gg) * DD + c4*4);
    }
  };
  auto write_stage = [&](int c) {
    char* buf = &lds[c & 1][0];
    if (WS) {
      *(u16x8*)(buf + tid*16)        = ab[0];
      *(u16x8*)(buf + 8192 + tid*16) = ab[1];
    } else {
      u16x8 r0, r1;
      #pragma unroll
      for (int j = 0; j < 8; ++j) { r0[j] = f2bf(af_[0][j]); r1[j] = f2bf(af_[1][j]); }
      *(u16x8*)(buf + tid*16)        = r0;
      *(u16x8*)(buf + 8192 + tid*16) = r1;
    }
    // xT butterfly (verified v6): lane ends with d = c4*4+gg, n-quad n4
    char* xt = buf + 16384 + wb*8192;
    const int d = c4*4 + gg;
    #pragma unroll
    for (int s = 0; s < 4; ++s) {
      const int n4 = s*4 + wm;
      unsigned u0 = pk2(xv[s].x, xv[s].y);
      unsigned u1 = pk2(xv[s].z, xv[s].w);
      unsigned t0 = __shfl_xor(u0, 32);
      unsigned t1 = __shfl_xor(u1, 32);
      unsigned v0 = (gg & 2) ? t1 : u0;
      unsigned v1 = (gg & 2) ? u1 : t0;
      unsigned s0 = __shfl_xor(v0, 16);
      unsigned s1 = __shfl_xor(v1, 16);
      unsigned F0 = (gg & 1) ? ((s0 >> 16) | (v0 & 0xFFFF0000u))
                             : ((v0 & 0xFFFFu) | (s0 << 16));
      unsigned F1 = (gg & 1) ? ((s1 >> 16) | (v1 & 0xFFFF0000u))
                             : ((v1 & 0xFFFFu) | (s1 << 16));
      uint2 o2; o2.x = F0; o2.y = F1;
      *(uint2*)(xt + d*128 + (((n4 >> 1) ^ (d & 7)) * 16) + (n4 & 1)*8) = o2;
    }
  };

  f32x4 acc[2][4];
  #pragma unroll
  for (int mt = 0; mt < 2; ++mt)
    #pragma unroll
    for (int dt = 0; dt < 4; ++dt) acc[mt][dt] = f32x4{0.f,0.f,0.f,0.f};

  load_adj(0); load_x(0);

  #pragma unroll 2
  for (int c = 0; c < 8; ++c) {
    write_stage(c);                 // into buf c&1 (its last readers were chunk c-2,
    __syncthreads();                //   done before iteration c-1's barrier)
    if (c < 7) { load_adj(c+1); load_x(c+1); }   // in flight across the MFMA phase
    {
      const char* buf  = &lds[c & 1][0];
      const char* adjL = buf;
      const char* xt   = buf + 16384 + wb*8192;
      #pragma unroll
      for (int kl = 0; kl < 2; ++kl) {
        const int sw = ((kl*4 + gg) ^ (l15 & 7)) * 16;
        bf16x8 afr[2], bfx[4];
        #pragma unroll
        for (int mt = 0; mt < 2; ++mt)
          afr[mt] = __builtin_bit_cast(bf16x8,
              *(const u16x8*)(adjL + (wm*32 + mt*16 + l15)*128 + sw));
        #pragma unroll
        for (int dt = 0; dt < 4; ++dt)
          bfx[dt] = __builtin_bit_cast(bf16x8,
              *(const u16x8*)(xt + (dt*16 + l15)*128 + sw));
        #pragma unroll
        for (int mt = 0; mt < 2; ++mt)
          #pragma unroll
          for (int dt = 0; dt < 4; ++dt)
            acc[mt][dt] = __builtin_amdgcn_mfma_f32_16x16x32_bf16(afr[mt], bfx[dt],
                                                                  acc[mt][dt], 0,0,0);
      }
    }
  }

  // epilogue: H store (bf16, low half of each d_out row) — verified pattern
  const int bt = bt0 + wb;
  #pragma unroll
  for (int mt = 0; mt < 2; ++mt)
    #pragma unroll
    for (int dt = 0; dt < 4; ++dt)
      #pragma unroll
      for (int r = 0; r < 4; ++r) {
        int m = mb*128 + wm*32 + mt*16 + gg*4 + r;   // C row = (lane>>4)*4 + reg
        int d = dt*16 + l15;
        *(unsigned short*)(hout + ((size_t)bt*M_N + m)*256 + 2*d)
            = f2bf(acc[mt][dt][r]);
      }
}

// ---------------- Kernel B (unchanged, verified) ----------------
__global__ __launch_bounds__(256, 4)
void route_mm(const char* __restrict__ hin,
              const float* __restrict__ wgt,
              const float* __restrict__ bias,
              float* __restrict__ outg)
{
  __shared__ unsigned short wb[128 * WROW];

  const int m0    = blockIdx.x * 2;
  const int btblk = blockIdx.y * 64;
  const int tid   = threadIdx.x;
  const int lane  = tid & 63;
  const int wv    = tid >> 6;
  const int l15   = lane & 15;
  const int gg    = lane >> 4;
  const int dp    = tid & 31;
  const int lo    = tid >> 5;

  { const float* q = wgt + ((size_t)m0*64 + dp*2)*64 + lo*8;
    f32x8 w0 = *(const f32x8*)q;          f32x8 w1 = *(const f32x8*)(q+64);
    f32x8 w2 = *(const f32x8*)(q+4096);   f32x8 w3 = *(const f32x8*)(q+4160);
    #pragma unroll
    for (int e = 0; e < 8; ++e) {
      int lrow = lo*8 + e;
      unsigned v0 = pk2(w0[e], w1[e]);
      unsigned v1 = pk2(w2[e], w3[e]);
      *(unsigned*)(wb + lrow*WROW + dp*2)        = v0;
      *(unsigned*)(wb + (64 + lrow)*WROW + dp*2) = v1;
    }
  }
  __syncthreads();

  const int btw0 = btblk + wv*16;

  #pragma unroll
  for (int mm = 0; mm < 2; ++mm) {
    const int m = m0 + mm;
    bf16x8 afr[2];
    #pragma unroll
    for (int ks = 0; ks < 2; ++ks) {
      const char* hp = hin + ((size_t)(btw0 + l15)*M_N + m)*256 + ks*64 + gg*16;
      afr[ks] = __builtin_bit_cast(bf16x8, *(const u16x8*)hp);
    }
    f32x4 acc[4];
    #pragma unroll
    for (int lt = 0; lt < 4; ++lt) acc[lt] = f32x4{0.f,0.f,0.f,0.f};
    #pragma unroll
    for (int lt = 0; lt < 4; ++lt)
      #pragma unroll
      for (int ks = 0; ks < 2; ++ks) {
        bf16x8 bfr = __builtin_bit_cast(bf16x8,
            *(const u16x8*)(wb + (mm*64 + lt*16 + l15)*WROW + ks*32 + gg*8));
        acc[lt] = __builtin_amdgcn_mfma_f32_16x16x32_bf16(afr[ks], bfr, acc[lt], 0,0,0);
      }
    #pragma unroll
    for (int lt = 0; lt < 4; ++lt) {
      float bv = bias[m*64 + lt*16 + l15];
      #pragma unroll
      for (int r = 0; r < 4; ++r) {
        size_t row = (size_t)(btw0 + gg*4 + r)*M_N + m;
        outg[row*64 + lt*16 + l15] = acc[lt][r] + bv;
      }
    }
  }
}

extern "C" void kernel_launch(void* const* d_in, const int* in_sizes, int n_in,
                              void* d_out, int out_size, void* d_ws, size_t ws_size,
                              hipStream_t stream) {
  const float* xg   = (const float*)d_in[0];
  const float* adjg = (const float*)d_in[1];
  const float* wgt  = (const float*)d_in[2];
  const float* bg   = (const float*)d_in[3];

  const size_t adj_bf_bytes = (size_t)M_N * M_N * 2;   // 512 KB
  if (ws_size >= adj_bf_bytes) {
    unsigned short* wsadj = (unsigned short*)d_ws;
    prep_adj<<<dim3(M_N * M_N / (256 * 8)), dim3(256), 0, stream>>>(adjg, wsadj);
    gconv_h<true><<<dim3(1536), dim3(512), 0, stream>>>(
        xg, adjg, wsadj, (char*)d_out);
  } else {
    gconv_h<false><<<dim3(1536), dim3(512), 0, stream>>>(
        xg, adjg, nullptr, (char*)d_out);
  }
  route_mm<<<dim3(M_N/2, BT_TOT/64), dim3(256), 0, stream>>>(
      (const char*)d_out, wgt, bg, (float*)d_out);
}